// Round 1
// baseline (183.762 us; speedup 1.0000x reference)
//
#include <hip/hip_runtime.h>

// NeuSSampler PDF importance resampling.
// Per ray: w = weights + 1e-5; pdf = w/sum(w); cdf = [0, min(1,cumsum(pdf))];
// 65 mid-bin queries u_j=(2j+1)/130; searchsorted(right) + linear interp into
// existing_bins; euclidean = b*far + (1-b)*near.
//
// Layout: one wave (64 lanes) per ray, 4 rays per 256-thread block.
//  - lane loads weight pair as float2 (coalesced)
//  - shfl_up inclusive scan of pair sums (6 steps)
//  - CDF (129) + bins row (129) staged in LDS per wave
//  - lane j binary-searches query j; query 64 done uniformly by all lanes
//    (LDS broadcast, zero divergence), stored by lane 0.

__global__ __launch_bounds__(256) void neus_sampler_kernel(
    const float* __restrict__ weights,
    const float* __restrict__ bins_g,
    const float* __restrict__ nears,
    const float* __restrict__ fars,
    float* __restrict__ out,
    int R)
{
    constexpr int S  = 128;   // existing samples per ray
    constexpr int SE = 129;   // bin edges per ray
    constexpr int NB = 65;    // output bins per ray
    constexpr float HPAD = 1e-5f;

    __shared__ float s_cdf[4][SE + 1];
    __shared__ float s_bin[4][SE + 1];

    const int lane = threadIdx.x & 63;
    const int wv   = threadIdx.x >> 6;
    const int ray  = blockIdx.x * 4 + wv;
    const bool valid = ray < R;
    const int cray = valid ? ray : (R - 1);   // safe row for inactive tail waves

    // ---- weights: 2 per lane, vectorized (row start is 512B-aligned) ----
    const float2 wpair =
        reinterpret_cast<const float2*>(weights + (size_t)cray * S)[lane];
    const float w0 = wpair.x + HPAD;
    const float w1 = wpair.y + HPAD;

    // ---- stage existing_bins row into LDS (coalesced) ----
    const float* brow = bins_g + (size_t)cray * SE;
    s_bin[wv][2 * lane]     = brow[2 * lane];
    s_bin[wv][2 * lane + 1] = brow[2 * lane + 1];
    if (lane == 0) s_bin[wv][S] = brow[S];

    // ---- wave inclusive scan of pair sums ----
    float ps = w0 + w1;
    #pragma unroll
    for (int off = 1; off < 64; off <<= 1) {
        float n = __shfl_up(ps, off, 64);
        if (lane >= off) ps += n;
    }
    const float total   = __shfl(ps, 63, 64);
    const float padding = fmaxf(1e-5f - total, 0.0f);   // relu(EPS - w_sum)
    const float padc    = padding * (1.0f / S);
    const float inv     = 1.0f / (total + padding);

    // cdf[k+1] = min(1, cumsum_k * inv), cumsum_k includes +(k+1)*padc
    // lane owns elements k = 2*lane (raw cum = ps - w1) and k = 2*lane+1 (ps)
    s_cdf[wv][2 * lane + 1] =
        fminf(1.0f, (ps - w1 + (float)(2 * lane + 1) * padc) * inv);
    s_cdf[wv][2 * lane + 2] =
        fminf(1.0f, (ps + (float)(2 * lane + 2) * padc) * inv);
    if (lane == 0) s_cdf[wv][0] = 0.0f;

    __syncthreads();

    const float nearv = nears[cray];
    const float farv  = fars[cray];
    const float* cdf = s_cdf[wv];
    const float* bnr = s_bin[wv];
    float* orow = out + (size_t)ray * NB;

    auto sample = [&](int j) -> float {
        const float u = (float)(2 * j + 1) * (1.0f / (2.0f * NB));
        // searchsorted(cdf[0..128], u, side='right'): first idx with cdf>u
        int lo = 0, hi = SE;            // insertion point in [0, 129]
        while (lo < hi) {
            const int mid = (lo + hi) >> 1;
            if (cdf[mid] <= u) lo = mid + 1; else hi = mid;
        }
        int above = lo;     if (above > S) above = S;
        int below = lo - 1; if (below < 0) below = 0;
        const float c0 = cdf[below], c1 = cdf[above];
        const float b0 = bnr[below], b1 = bnr[above];
        const float denom = c1 - c0;    // >= 0 (cdf monotone)
        // nan_to_num(nan/inf -> 0) then clip: denom==0 -> 0 (u>=c0 always)
        const float t = (denom > 0.0f)
            ? fminf(fmaxf((u - c0) / denom, 0.0f), 1.0f) : 0.0f;
        const float b = fmaf(t, b1 - b0, b0);
        return b * farv + (1.0f - b) * nearv;
    };

    const float r_own  = sample(lane);  // queries 0..63
    const float r_last = sample(64);    // uniform across lanes (broadcast reads)

    if (valid) {
        orow[lane] = r_own;
        if (lane == 0) orow[NB - 1] = r_last;
    }
}

extern "C" void kernel_launch(void* const* d_in, const int* in_sizes, int n_in,
                              void* d_out, int out_size, void* d_ws, size_t ws_size,
                              hipStream_t stream) {
    const float* weights = (const float*)d_in[0];   // [R,128,1]
    const float* ebins   = (const float*)d_in[1];   // [R,129]
    const float* nears   = (const float*)d_in[2];   // [R,1]
    const float* fars    = (const float*)d_in[3];   // [R,1]
    float* out = (float*)d_out;                     // [R,65]
    const int R = in_sizes[0] / 128;
    const int blocks = (R + 3) / 4;                 // 4 rays (waves) per block
    hipLaunchKernelGGL(neus_sampler_kernel, dim3(blocks), dim3(256), 0, stream,
                       weights, ebins, nears, fars, out, R);
}

// Round 2
// 171.752 us; speedup vs baseline: 1.0699x; 1.0699x over previous
//
#include <hip/hip_runtime.h>

// NeuSSampler PDF importance resampling — segment-parallel formulation.
//
// One wave per ray. Lane l loads weight pair (w[2l], w[2l+1]) and bin pair,
// wave-scans pair sums -> lane holds cdf[2l+1], cdf[2l+2] in registers;
// cdf[2l] via shfl_up. Queries u_j = (2j+1)/130 are a fixed arithmetic
// progression, so segment k = [cdf[k], cdf[k+1]) covers exactly
// j in [jf(cdf[k]), jf(cdf[k+1])) with jf(c) = ceil(65c - 0.5).
// Adjacent lanes evaluate jf on bit-identical shuffled values -> the ranges
// exactly partition [0,65): every output written exactly once, no search,
// no LDS, no __syncthreads.
//
// searchsorted(right) semantics preserved: duplicate cdf entries -> last
// duplicate wins (its upper edge is the first strictly-greater value);
// u beyond cdf[128] (defensive) -> lane 63's segment-127 bound is +inf and
// t clips to 1 -> bins[128], identical to the reference's clipped gather.

__global__ __launch_bounds__(256) void neus_sampler_kernel(
    const float* __restrict__ weights,
    const float* __restrict__ bins_g,
    const float* __restrict__ nears,
    const float* __restrict__ fars,
    float* __restrict__ out,
    int R)
{
    constexpr int S  = 128;   // weights per ray
    constexpr int NB = 65;    // output samples per ray
    constexpr float HPAD = 1e-5f;

    const int lane = threadIdx.x & 63;
    const int ray  = blockIdx.x * 4 + (threadIdx.x >> 6);
    if (ray >= R) return;     // wave-uniform exit (ray is per-wave)

    // ---- coalesced vector loads: 2 weights + 2 bin edges per lane ----
    const float2 wpair =
        reinterpret_cast<const float2*>(weights + (size_t)ray * S)[lane];
    const float* brow = bins_g + (size_t)ray * (S + 1);
    const float2 bpair = reinterpret_cast<const float2*>(brow)[lane];
    const float b_last = brow[S];          // broadcast (1 txn/wave)

    const float w1 = wpair.y + HPAD;
    float ps = (wpair.x + HPAD) + w1;      // pair sum

    // ---- wave inclusive scan of pair sums: ps = cumsum(w)[2l+1] ----
    #pragma unroll
    for (int off = 1; off < 64; off <<= 1) {
        float n = __shfl_up(ps, off, 64);
        if (lane >= off) ps += n;
    }
    const float total   = __shfl(ps, 63, 64);
    const float padding = fmaxf(1e-5f - total, 0.0f);   // relu(EPS - w_sum)
    const float padc    = padding * (1.0f / S);
    const float inv     = 1.0f / (total + padding);

    // ---- per-lane cdf edges (registers only) ----
    const float c_hi  = fminf(1.0f, fmaf((float)(2 * lane + 2), padc, ps) * inv);
    const float c_mid = fminf(1.0f, fmaf((float)(2 * lane + 1), padc, ps - w1) * inv);
    float c_lo = __shfl_up(c_hi, 1, 64);
    if (lane == 0) c_lo = 0.0f;            // cdf[0]

    float b2 = __shfl_down(bpair.x, 1, 64);  // bins[2l+2]
    if (lane == 63) b2 = b_last;             // bins[128]

    const float nearv = nears[ray];
    const float farv  = fars[ray];
    const float fmn   = farv - nearv;
    float* orow = out + (size_t)ray * NB;

    // first query index j with u_j >= c  (u_j = (2j+1)/130)
    auto jf = [](float c) -> int {
        int j = (int)ceilf(fmaf(65.0f, c, -0.5f));
        return j < 0 ? 0 : (j > NB ? NB : j);
    };

    const int j0 = jf(c_lo);
    const int j1 = jf(c_mid);
    const int j2 = (lane == 63) ? NB : jf(c_hi);   // last segment: bound = +inf

    // segment k=2l: [c_lo, c_mid), bins [bpair.x, bpair.y]
    {
        const float d = c_mid - c_lo;
        for (int j = j0; j < j1; ++j) {
            const float u = (float)(2 * j + 1) * (1.0f / 130.0f);
            float t = (d > 0.0f) ? (u - c_lo) / d : 0.0f;
            t = fminf(fmaxf(t, 0.0f), 1.0f);
            const float b = fmaf(t, bpair.y - bpair.x, bpair.x);
            orow[j] = fmaf(b, fmn, nearv);
        }
    }
    // segment k=2l+1: [c_mid, c_hi), bins [bpair.y, b2]
    {
        const float d = c_hi - c_mid;
        for (int j = j1; j < j2; ++j) {
            const float u = (float)(2 * j + 1) * (1.0f / 130.0f);
            float t = (d > 0.0f) ? (u - c_mid) / d : 0.0f;
            t = fminf(fmaxf(t, 0.0f), 1.0f);
            const float b = fmaf(t, b2 - bpair.y, bpair.y);
            orow[j] = fmaf(b, fmn, nearv);
        }
    }
}

extern "C" void kernel_launch(void* const* d_in, const int* in_sizes, int n_in,
                              void* d_out, int out_size, void* d_ws, size_t ws_size,
                              hipStream_t stream) {
    const float* weights = (const float*)d_in[0];   // [R,128,1]
    const float* ebins   = (const float*)d_in[1];   // [R,129]
    const float* nears   = (const float*)d_in[2];   // [R,1]
    const float* fars    = (const float*)d_in[3];   // [R,1]
    float* out = (float*)d_out;                     // [R,65]
    const int R = in_sizes[0] / 128;
    const int blocks = (R + 3) / 4;                 // 4 rays (waves) per block
    hipLaunchKernelGGL(neus_sampler_kernel, dim3(blocks), dim3(256), 0, stream,
                       weights, ebins, nears, fars, out, R);
}

// Round 3
// 163.225 us; speedup vs baseline: 1.1258x; 1.0522x over previous
//
#include <hip/hip_runtime.h>

// NeuSSampler PDF importance resampling — segment-parallel, DPP scan,
// division-free inner loop.
//
// One wave per ray, 4 waves/block. Lane l owns weights/bins pair (2l, 2l+1).
// Wave-wide inclusive scan of pair sums via the classic gfx9 DPP sequence
// (row_shr:1/2/4/8 + row_bcast:15 rmask 0xa + row_bcast:31 rmask 0xc) — 6
// v_add_f32_dpp, no LDS crossbar.
// Queries u_j=(2j+1)/130 are an arithmetic progression, so segment k covers
// exactly j in [jf(cdf[k]), jf(cdf[k+1])), jf(c)=ceil(65c-0.5). Shared edges
// are bit-identical across lanes (shuffled), so ranges tile [0,65) exactly.
// Per segment: one v_rcp, then t advances incrementally (t += r/65) — no
// division in the loop.
//
// Degenerate cases: duplicate cdf entries -> empty segment (jf equal), and
// d==0 with nonempty range (lane63 forced j2=65) -> t = ±inf/NaN ->
// fmaxf(NaN,0)=0 / clip(inf)=1 -> bins[below]/bins[128], matching the
// reference's nan_to_num + clip gather semantics.

#define DPP_FADD(x, ctrl, rmask)                                             \
    ((x) + __int_as_float(__builtin_amdgcn_update_dpp(                       \
               0, __float_as_int(x), (ctrl), (rmask), 0xf, true)))

__global__ __launch_bounds__(256) void neus_sampler_kernel(
    const float* __restrict__ weights,
    const float* __restrict__ bins_g,
    const float* __restrict__ nears,
    const float* __restrict__ fars,
    float* __restrict__ out,
    int R)
{
    constexpr int S  = 128;   // weights per ray
    constexpr int NB = 65;    // output samples per ray
    constexpr float HPAD = 1e-5f;

    const int lane = threadIdx.x & 63;
    const int ray  = blockIdx.x * 4 + (threadIdx.x >> 6);
    if (ray >= R) return;                       // wave-uniform (no barriers)
    const int uray = __builtin_amdgcn_readfirstlane(ray);  // SGPR base addrs

    // ---- coalesced vector loads: 2 weights + 2 bin edges per lane ----
    const float2 wpair =
        reinterpret_cast<const float2*>(weights + (size_t)uray * S)[lane];
    const float* brow = bins_g + (size_t)uray * (S + 1);
    const float2 bpair = reinterpret_cast<const float2*>(brow)[lane];
    const float b_last = brow[S];               // uniform -> s_load

    const float w1 = wpair.y + HPAD;
    float ps = (wpair.x + HPAD) + w1;           // pair sum

    // ---- wave64 inclusive scan (DPP): ps = cumsum(w)[2l+1] ----
    ps = DPP_FADD(ps, 0x111, 0xf);  // row_shr:1
    ps = DPP_FADD(ps, 0x112, 0xf);  // row_shr:2
    ps = DPP_FADD(ps, 0x114, 0xf);  // row_shr:4
    ps = DPP_FADD(ps, 0x118, 0xf);  // row_shr:8
    ps = DPP_FADD(ps, 0x142, 0xa);  // row_bcast:15 -> rows 1,3
    ps = DPP_FADD(ps, 0x143, 0xc);  // row_bcast:31 -> rows 2,3

    const float total =
        __int_as_float(__builtin_amdgcn_readlane(__float_as_int(ps), 63));
    const float padding = fmaxf(1e-5f - total, 0.0f);   // relu(EPS - w_sum)
    const float padc    = padding * (1.0f / S);
    const float inv     = __builtin_amdgcn_rcpf(total + padding);

    // ---- per-lane cdf edges (registers only) ----
    const float c_hi  = fminf(1.0f, fmaf((float)(2 * lane + 2), padc, ps) * inv);
    const float c_mid = fminf(1.0f, fmaf((float)(2 * lane + 1), padc, ps - w1) * inv);
    float c_lo = __shfl_up(c_hi, 1, 64);
    if (lane == 0) c_lo = 0.0f;                 // cdf[0]
    float b2 = __shfl_down(bpair.x, 1, 64);     // bins[2l+2]
    if (lane == 63) b2 = b_last;                // bins[128]

    const float nearv = nears[uray];            // uniform -> s_load
    const float farv  = fars[uray];
    const float fmn   = farv - nearv;
    float* orow = out + (size_t)uray * NB;

    // first query index j with u_j >= c  (u_j = (2j+1)/130)
    auto jf = [](float c) -> int {
        int j = (int)ceilf(fmaf(65.0f, c, -0.5f));
        return j < 0 ? 0 : (j > NB ? NB : j);
    };

    const int j0 = jf(c_lo);
    const int j2 = (lane == 63) ? NB : jf(c_hi);   // last segment: open top
    int j1 = jf(c_mid);
    j1 = j1 < j0 ? j0 : (j1 > j2 ? j2 : j1);       // tile [j0,j2) exactly

    // segment k=2l: [c_lo, c_mid), bins [bpair.x, bpair.y]
    if (j1 > j0) {                                  // => c_mid > c_lo
        const float r  = __builtin_amdgcn_rcpf(c_mid - c_lo);
        const float dt = r * (1.0f / 65.0f);
        const float bd = bpair.y - bpair.x;
        float u = (float)(2 * j0 + 1) * (1.0f / 130.0f);
        float t = (u - c_lo) * r;
        for (int j = j0; j < j1; ++j) {
            const float tc = fminf(fmaxf(t, 0.0f), 1.0f);
            orow[j] = fmaf(fmaf(tc, bd, bpair.x), fmn, nearv);
            t += dt;
        }
    }
    // segment k=2l+1: [c_mid, c_hi), bins [bpair.y, b2]
    if (j2 > j1) {
        const float r  = __builtin_amdgcn_rcpf(c_hi - c_mid);  // inf if d==0
        const float dt = r * (1.0f / 65.0f);
        const float bd = b2 - bpair.y;
        float u = (float)(2 * j1 + 1) * (1.0f / 130.0f);
        float t = (u - c_mid) * r;
        for (int j = j1; j < j2; ++j) {
            const float tc = fminf(fmaxf(t, 0.0f), 1.0f);  // NaN-safe: ->0
            orow[j] = fmaf(fmaf(tc, bd, bpair.y), fmn, nearv);
            t += dt;
        }
    }
}

extern "C" void kernel_launch(void* const* d_in, const int* in_sizes, int n_in,
                              void* d_out, int out_size, void* d_ws, size_t ws_size,
                              hipStream_t stream) {
    const float* weights = (const float*)d_in[0];   // [R,128,1]
    const float* ebins   = (const float*)d_in[1];   // [R,129]
    const float* nears   = (const float*)d_in[2];   // [R,1]
    const float* fars    = (const float*)d_in[3];   // [R,1]
    float* out = (float*)d_out;                     // [R,65]
    const int R = in_sizes[0] / 128;
    const int blocks = (R + 3) / 4;                 // 4 rays (waves) per block
    hipLaunchKernelGGL(neus_sampler_kernel, dim3(blocks), dim3(256), 0, stream,
                       weights, ebins, nears, fars, out, R);
}